// Round 18
// baseline (4161.733 us; speedup 1.0000x reference)
//
#include <hip/hip_runtime.h>
#include <hip/hip_fp16.h>

#define HID    1024
#define G4     4096
#define TT     512
#define BB     8
#define VOCABN 32000
#define NBLK   256

typedef _Float16 f16x2 __attribute__((ext_vector_type(2)));
typedef _Float16 f16x8 __attribute__((ext_vector_type(8)));
typedef float    f32x4 __attribute__((ext_vector_type(4)));
typedef unsigned long long u64;

union U2F { u64 q[2]; f16x8 v; };

__device__ __forceinline__ float sigf(float x) { return 1.0f / (1.0f + expf(-x)); }

// ---------------- f32 -> f16 convert ----------------
__global__ void cvt_f16_kernel(const float* __restrict__ src, __half* __restrict__ dst, int n4) {
  int i = blockIdx.x * blockDim.x + threadIdx.x;
  int stride = gridDim.x * blockDim.x;
  for (; i < n4; i += stride) {
    f32x4 v = ((const f32x4*)src)[i];
    ((__half2*)dst)[2 * i]     = __floats2half2_rn(v[0], v[1]);
    ((__half2*)dst)[2 * i + 1] = __floats2half2_rn(v[2], v[3]);
  }
}

// ---------------- embedding gather: xe[t*8+b] = emb16[x[b][t]] ----------------
__global__ void gather_kernel(const int* __restrict__ x, const __half* __restrict__ emb,
                              __half* __restrict__ xe) {
  int gid = blockIdx.x * 256 + threadIdx.x;   // 4096 rows * 128 chunks of 16B
  int row = gid >> 7, ch = gid & 127;
  int t = row >> 3, b = row & 7;
  int tok = x[b * TT + t];
  ((f32x4*)(xe + (size_t)row * HID))[ch] = ((const f32x4*)(emb + (size_t)tok * HID))[ch];
}

__device__ __forceinline__ void storeC(float* p, float v)  { *p = v; }
__device__ __forceinline__ void storeC(__half* p, float v) { *p = __float2half(v); }

// ------- 128x128 f16 MFMA GEMM: C = A[M,1024] * B[N,1024]^T (+bias) -------
// XL=true: write to X0T layout [tau][gate][unit][batch] (half)
template <typename CT, bool XL>
__global__ void __launch_bounds__(256) gemm_f16_kernel(
    const _Float16* __restrict__ A, const _Float16* __restrict__ B,
    CT* __restrict__ C, const float* __restrict__ bias, int N)
{
  __shared__ _Float16 As[128 * 40];
  __shared__ _Float16 Bs[128 * 40];
  const int tid = threadIdx.x;
  const int tn = blockIdx.x, tm = blockIdx.y;
  const int wave = tid >> 6, lane = tid & 63;
  const int wm = wave >> 1, wn = wave & 1;
  const int lr = lane & 15, lk = ((lane >> 4) << 3);
  const _Float16* Ab = A + (size_t)tm * 128 * HID;
  const _Float16* Bb = B + (size_t)tn * 128 * HID;
  const int r0 = tid >> 2, c8 = (tid & 3) * 8;
  f32x4 acc[4][4] = {};
  f32x4 a0r, a1r, b0r, b1r;
  a0r = *(const f32x4*)(Ab + (size_t)r0 * HID + c8);
  a1r = *(const f32x4*)(Ab + (size_t)(64 + r0) * HID + c8);
  b0r = *(const f32x4*)(Bb + (size_t)r0 * HID + c8);
  b1r = *(const f32x4*)(Bb + (size_t)(64 + r0) * HID + c8);
  for (int kt = 0; kt < 32; ++kt) {
    __syncthreads();
    *(f32x4*)(As + (size_t)r0 * 40 + c8)        = a0r;
    *(f32x4*)(As + (size_t)(64 + r0) * 40 + c8) = a1r;
    *(f32x4*)(Bs + (size_t)r0 * 40 + c8)        = b0r;
    *(f32x4*)(Bs + (size_t)(64 + r0) * 40 + c8) = b1r;
    __syncthreads();
    if (kt < 31) {
      int ko = (kt + 1) * 32 + c8;
      a0r = *(const f32x4*)(Ab + (size_t)r0 * HID + ko);
      a1r = *(const f32x4*)(Ab + (size_t)(64 + r0) * HID + ko);
      b0r = *(const f32x4*)(Bb + (size_t)r0 * HID + ko);
      b1r = *(const f32x4*)(Bb + (size_t)(64 + r0) * HID + ko);
    }
    f16x8 af[4], bf[4];
    #pragma unroll
    for (int m = 0; m < 4; ++m) af[m] = *(const f16x8*)(As + (wm * 64 + m * 16 + lr) * 40 + lk);
    #pragma unroll
    for (int n = 0; n < 4; ++n) bf[n] = *(const f16x8*)(Bs + (wn * 64 + n * 16 + lr) * 40 + lk);
    #pragma unroll
    for (int m = 0; m < 4; ++m)
      #pragma unroll
      for (int n = 0; n < 4; ++n)
        acc[m][n] = __builtin_amdgcn_mfma_f32_16x16x32_f16(af[m], bf[n], acc[m][n], 0, 0, 0);
  }
  const int mrow = ((lane >> 4) << 2);
  #pragma unroll
  for (int n = 0; n < 4; ++n) {
    int gc = tn * 128 + wn * 64 + n * 16 + lr;
    float bc = bias ? bias[gc] : 0.0f;
    #pragma unroll
    for (int m = 0; m < 4; ++m) {
      int gr0 = tm * 128 + wm * 64 + m * 16 + mrow;
      #pragma unroll
      for (int r = 0; r < 4; ++r) {
        float v = acc[m][n][r] + bc;
        if constexpr (XL) {
          int gr = gr0 + r;
          int idx = ((gr >> 3) * 4 + (gc >> 10)) * 8192 + (gc & 1023) * 8 + (gr & 7);
          storeC(C + idx, v);
        } else {
          storeC(C + (size_t)(gr0 + r) * N + gc, v);
        }
      }
    }
  }
}

// ---------------- persistent LSTM, MFMA gates, cross-tick h1+X0 prefetch ----------------
// 256 WGs x 256 threads (4 waves = 4 K-quarters). Block owns 4 units/layer.
// Weights as persistent MFMA A-fragments in VGPRs; h [slot][b][k] f16 at LLC.
// h loads: global_load_dwordx4 sc0 sc1 (cache-bypass, line-perfect; R16-proven).
// h1(tau-2) is confirmed by the PREVIOUS tick's poll -> issue its loads right after
// that poll passes; their RTT hides under the tick boundary. Critical vmcnt(0)
// then covers only the 16 h0 loads. X0 prefetched post-flag (R17-proven).
// Sync: ONE barrier/tick + dependency-subset flag polling (R15-proven).
template <bool COOP>
__global__ void __launch_bounds__(256, 1) lstm_kernel(
    const __half* __restrict__ wh0, const __half* __restrict__ wx1, const __half* __restrict__ wh1,
    const __half* __restrict__ X0T, const float* __restrict__ wxb1,
    u64* __restrict__ h0t, u64* __restrict__ h1t, float* __restrict__ cgl,
    __half* __restrict__ outf, float* __restrict__ hc_out, unsigned* __restrict__ bs,
    int tau0, int tau1)
{
  __shared__ float part[8 * 16 * 9];   // [wave*2+layer][gaterow][batch(pad 9)]

  const int tid  = threadIdx.x;
  const int u0   = blockIdx.x * 4;
  const int wv   = tid >> 6, lane = tid & 63;
  const int rr   = lane & 15;               // gate-row: g = rr&3, uu = rr>>2
  const int kc   = (lane >> 4) * 8;         // k-chunk within K=32
  const int bcol = lane & 7;                // batch col (cols 8-15 duplicate 0-7)
  const int kio  = (wv * 256 + kc) >> 2;    // per-wave k-offset in u64 units

  // ---- pin weights as A-fragments: wave wv holds k in [wv*256, wv*256+256) ----
  f16x8 w0f[8], w1f[8], w2f[8];
  {
    const size_t wrow = (size_t)((rr & 3) * HID + u0 + (rr >> 2)) * HID;
    #pragma unroll
    for (int m = 0; m < 8; ++m) {
      const int kb = wv * 256 + m * 32 + kc;
      w0f[m] = *(const f16x8*)(wh0 + wrow + kb);
      w1f[m] = *(const f16x8*)(wx1 + wrow + kb);
      w2f[m] = *(const f16x8*)(wh1 + wrow + kb);
    }
  }

  float bi0 = 0, bi1 = 0, bi2 = 0, bi3 = 0;
  if (tid >= 32 && tid < 64) {
    int uu = (tid >> 3) & 3, u = u0 + uu;
    bi0 = wxb1[u]; bi1 = wxb1[HID + u]; bi2 = wxb1[2 * HID + u]; bi3 = wxb1[3 * HID + u];
  }

  // cell state: register in COOP (thread owns (l,uu,b) across all ticks)
  float creg = 0.0f;
  if constexpr (!COOP) {
    if (tid < 64) {
      const int l = tid >> 5, uu = (tid >> 3) & 3, b = tid & 7;
      creg = cgl[(size_t)l * (HID * BB) + (u0 + uu) * BB + b];
    }
  }

  // X0 prefetch registers (COOP): hold X0[tau] for the upcoming tick
  float x0p0 = 0, x0p1 = 0, x0p2 = 0, x0p3 = 0;
  if constexpr (COOP) {
    if (tid < 32 && tau0 < TT) {
      const __half* xq = X0T + (size_t)tau0 * 4 * 8192 + u0 * 8 + tid;
      x0p0 = __half2float(xq[0]);
      x0p1 = __half2float(xq[8192]);
      x0p2 = __half2float(xq[2 * 8192]);
      x0p3 = __half2float(xq[3 * 8192]);
    }
  }

  // h1 prefetch: issue loads for the FIRST iteration (slot tau0&1 = h1(tau0-2),
  // memset zeros / published before this launch -> quiescent).
  U2F hf0[8], hf1[8];
  {
    const u64* s1 = h1t + (tau0 & 1) * 2048 + bcol * 256;
    #pragma unroll
    for (int m = 0; m < 8; ++m) {
      asm volatile("global_load_dwordx4 %0, %1, off sc0 sc1"
                   : "=v"(hf1[m].v) : "v"(s1 + kio + m * 8));
    }
  }

  for (int tau = tau0; tau < tau1; ++tau) {
    // X0 values for this tick: from prefetch (COOP) or loaded inline (fallback)
    float x0r0 = 0, x0r1 = 0, x0r2 = 0, x0r3 = 0;
    if constexpr (COOP) {
      x0r0 = x0p0; x0r1 = x0p1; x0r2 = x0p2; x0r3 = x0p3;
    } else {
      if (tid < 32 && tau < TT) {
        const __half* xp = X0T + (size_t)tau * 4 * 8192 + u0 * 8 + tid;
        x0r0 = __half2float(xp[0]);
        x0r1 = __half2float(xp[8192]);
        x0r2 = __half2float(xp[2 * 8192]);
        x0r3 = __half2float(xp[3 * 8192]);
      }
    }

    // ---- h0(tau-1) loads (h1 already in flight from previous tick's prefetch) ----
    {
      const u64* s0 = h0t + ((tau - 1) & 1) * 2048 + bcol * 256;
      #pragma unroll
      for (int m = 0; m < 8; ++m) {
        asm volatile("global_load_dwordx4 %0, %1, off sc0 sc1"
                     : "=v"(hf0[m].v) : "v"(s0 + kio + m * 8));
      }
      asm volatile("s_waitcnt vmcnt(0)" ::: "memory");
      __builtin_amdgcn_sched_barrier(0);
    }

    // ---- gates: acc0 = wh0.h0 ; acc1 = wx1.h0 + wh1.h1 (K-quarter partials) ----
    f32x4 a0 = {0.f, 0.f, 0.f, 0.f}, a1 = {0.f, 0.f, 0.f, 0.f};
    #pragma unroll
    for (int m = 0; m < 8; ++m) {
      a0 = __builtin_amdgcn_mfma_f32_16x16x32_f16(w0f[m], hf0[m].v, a0, 0, 0, 0);
      a1 = __builtin_amdgcn_mfma_f32_16x16x32_f16(w1f[m], hf0[m].v, a1, 0, 0, 0);
      a1 = __builtin_amdgcn_mfma_f32_16x16x32_f16(w2f[m], hf1[m].v, a1, 0, 0, 0);
    }
    // C layout: lane holds C[row=(lane>>4)*4+r][col=lane&15]; cols 8-15 garbage
    if ((lane & 15) < 8) {
      const int rb = (lane >> 4) * 4;
      #pragma unroll
      for (int r = 0; r < 4; ++r) {
        part[((wv * 2 + 0) * 16 + rb + r) * 9 + bcol] = a0[r];
        part[((wv * 2 + 1) * 16 + rb + r) * 9 + bcol] = a1[r];
      }
    }
    __syncthreads();   // the ONE block sync per tick

    // ---- update: 64 threads (wave 0) = 2 layers x 4 units x 8 batch ----
    float hn = 0.0f;
    bool act = false;
    if (tid < 64) {
      const int l = tid >> 5, uu = (tid >> 3) & 3, b = tid & 7;
      act = (l == 0) ? (tau < TT) : (tau >= 1);
      if (act) {
        float gs[4];
        #pragma unroll
        for (int g = 0; g < 4; ++g) {
          float s = 0.f;
          #pragma unroll
          for (int w = 0; w < 4; ++w)
            s += part[((w * 2 + l) * 16 + uu * 4 + g) * 9 + b];
          gs[g] = s;
        }
        float gi = gs[0], gf = gs[1], gg_ = gs[2], go = gs[3];
        if (l == 0) { gi += x0r0; gf += x0r1; gg_ += x0r2; go += x0r3; }
        else        { gi += bi0;  gf += bi1;  gg_ += bi2;  go += bi3;  }
        float co = creg;
        float cn = sigf(gf) * co + sigf(gi) * tanhf(gg_);
        hn = sigf(go) * tanhf(co);   // quirk: tanh of OLD cell
        creg = cn;
        const int u = u0 + uu;
        if (l == 1) {
          if (tau == TT) {            // final h1, c1
            hc_out[(size_t)(BB * HID) + b * HID + u] = hn;
            hc_out[3 * (size_t)(BB * HID) + b * HID + u] = cn;
          }
        } else if (tau == TT - 1) {   // final h0, c0
          hc_out[(size_t)b * HID + u] = hn;
          hc_out[2 * (size_t)(BB * HID) + b * HID + u] = cn;
        }
      }
      // pack 4 units into one u64 via shuffles; uu==0 lanes store (reuses l,uu,b)
      float s8 = __shfl_xor(hn, 8, 64);                 // partner uu^1
      __half2 p2 = __floats2half2_rn(hn, s8);
      unsigned pu; __builtin_memcpy(&pu, &p2, 4);
      unsigned q16 = __shfl_xor(pu, 16, 64);            // (uu+2, uu+3)
      u64 gr = (u64)pu | ((u64)q16 << 32);
      {
        const int l = tid >> 5, b = tid & 7;
        if (((tid >> 3) & 3) == 0 && act) {
          u64* dst = (l == 0)
              ? h0t + (tau & 1) * 2048 + b * 256 + (u0 >> 2)
              : h1t + ((tau - 1) & 1) * 2048 + b * 256 + (u0 >> 2);
          __hip_atomic_store(dst, gr, __ATOMIC_RELAXED, __HIP_MEMORY_SCOPE_AGENT);
        }
      }
    }

    if constexpr (COOP) {
      const int tick = tau - tau0 + 1;
      if (wv == 0) {
        asm volatile("s_waitcnt vmcnt(0)" ::: "memory");   // h stores acked at LLC
        if (tid == 0)
          __hip_atomic_store(&bs[blockIdx.x], (unsigned)tick,
                             __ATOMIC_RELAXED, __HIP_MEMORY_SCOPE_AGENT);
      }
      // X0 prefetch for tau+1 AFTER own flag is out (HBM latency overlaps poll)
      if (tid < 32 && tau + 1 < TT) {
        const __half* xq = X0T + (size_t)(tau + 1) * 4 * 8192 + u0 * 8 + tid;
        x0p0 = __half2float(xq[0]);
        x0p1 = __half2float(xq[8192]);
        x0p2 = __half2float(xq[2 * 8192]);
        x0p3 = __half2float(xq[3 * 8192]);
      }
      // outf store also off the flag path (no consumer in-kernel)
      if (tid >= 32 && tid < 64 && act) {
        const int uu = (tid >> 3) & 3, b = tid & 7;
        outf[((size_t)b * TT + (tau - 1)) * HID + u0 + uu] = __float2half(hn);
      }
      // dependency-subset poll: wave wv waits only its 64 producer blocks
      {
        const unsigned* fp = bs + wv * 64;
        int guard = 0;
        for (;;) {
          unsigned fa = __hip_atomic_load(&fp[lane], __ATOMIC_RELAXED, __HIP_MEMORY_SCOPE_AGENT);
          if (__all((int)fa >= tick)) break;
          if (++guard > 100000) break;   // failsafe: wrong answer, not a hang
          __builtin_amdgcn_s_sleep(1);
        }
        asm volatile("" ::: "memory");
      }
      // h1 prefetch for tau+1: h1((tau+1)-2) was published at tick tau and is
      // confirmed by the poll just passed -> quiescent; RTT hides in tick boundary.
      if (tau + 1 < tau1) {
        const u64* s1n = h1t + ((tau + 1) & 1) * 2048 + bcol * 256;
        #pragma unroll
        for (int m = 0; m < 8; ++m) {
          asm volatile("global_load_dwordx4 %0, %1, off sc0 sc1"
                       : "=v"(hf1[m].v) : "v"(s1n + kio + m * 8));
        }
      }
    } else {
      if (tid >= 32 && tid < 64 && act) {
        const int uu = (tid >> 3) & 3, b = tid & 7;
        outf[((size_t)b * TT + (tau - 1)) * HID + u0 + uu] = __float2half(hn);
      }
      if (tid < 64) {
        const int l = tid >> 5, uu = (tid >> 3) & 3, b = tid & 7;
        cgl[(size_t)l * (HID * BB) + (u0 + uu) * BB + b] = creg;
      }
      __syncthreads();
      if (tau + 1 < tau1) {
        const u64* s1n = h1t + ((tau + 1) & 1) * 2048 + bcol * 256;
        #pragma unroll
        for (int m = 0; m < 8; ++m) {
          asm volatile("global_load_dwordx4 %0, %1, off sc0 sc1"
                       : "=v"(hf1[m].v) : "v"(s1n + kio + m * 8));
        }
      }
    }
  }
}

extern "C" void kernel_launch(void* const* d_in, const int* in_sizes, int n_in,
                              void* d_out, int out_size, void* d_ws, size_t ws_size,
                              hipStream_t stream) {
  (void)in_sizes; (void)n_in; (void)out_size; (void)ws_size;
  const int*   x    = (const int*)  d_in[0];
  const float* embW = (const float*)d_in[1];
  const float* wxw  = (const float*)d_in[2];
  const float* wxb  = (const float*)d_in[3];
  const float* whw  = (const float*)d_in[4];
  float* out = (float*)d_out;

  char* ws = (char*)d_ws;
  size_t off = 0;
  auto alloc = [&](size_t bytes) { char* p = ws + off; off += (bytes + 255) & ~(size_t)255; return p; };
  __half*   emb16 = (__half*)alloc((size_t)VOCABN * HID * 2);
  __half*   xe16  = (__half*)alloc((size_t)4096 * HID * 2);
  __half*   wxw16 = (__half*)alloc((size_t)2 * G4 * HID * 2);
  __half*   whw16 = (__half*)alloc((size_t)2 * G4 * HID * 2);
  __half*   X0T   = (__half*)alloc((size_t)4096 * G4 * 2);
  __half*   outf  = (__half*)alloc((size_t)4096 * HID * 2);
  u64*      h0t   = (u64*)  alloc((size_t)2 * 2048 * 8);   // [slot][b][k] f16
  u64*      h1t   = (u64*)  alloc((size_t)2 * 2048 * 8);
  float*    cgl   = (float*) alloc((size_t)2 * HID * BB * 4);
  unsigned* bs    = (unsigned*)alloc(NBLK * 4);

  cvt_f16_kernel<<<2048, 256, 0, stream>>>(embW, emb16, VOCABN * HID / 4);
  cvt_f16_kernel<<<1024, 256, 0, stream>>>(wxw, wxw16, 2 * G4 * HID / 4);
  cvt_f16_kernel<<<1024, 256, 0, stream>>>(whw, whw16, 2 * G4 * HID / 4);
  gather_kernel<<<2048, 256, 0, stream>>>(x, emb16, xe16);
  hipMemsetAsync(h0t, 0, (size_t)2 * 2048 * 8, stream);
  hipMemsetAsync(h1t, 0, (size_t)2 * 2048 * 8, stream);
  hipMemsetAsync(cgl, 0, (size_t)2 * HID * BB * 4, stream);
  hipMemsetAsync(bs,  0, NBLK * 4, stream);

  // X0T[tau][gate][unit][batch] = xe @ wx0^T + b0   (f16)
  gemm_f16_kernel<__half, true><<<dim3(32, 32), 256, 0, stream>>>(
      (const _Float16*)xe16, (const _Float16*)wxw16, X0T, wxb, G4);

  const __half* wh0 = whw16;
  const __half* wx1 = wxw16 + (size_t)G4 * HID;
  const __half* wh1 = whw16 + (size_t)G4 * HID;
  const __half* X0c = X0T;
  const float*  wxb1 = wxb + G4;
  float* hc = out + (size_t)4096 * VOCABN;
  int tb = 0, te = TT + 1;
  void* args[] = {(void*)&wh0, (void*)&wx1, (void*)&wh1, (void*)&X0c, (void*)&wxb1,
                  (void*)&h0t, (void*)&h1t, (void*)&cgl, (void*)&outf, (void*)&hc,
                  (void*)&bs, (void*)&tb, (void*)&te};
  hipError_t rc = hipLaunchCooperativeKernel(
      reinterpret_cast<void*>(&lstm_kernel<true>), dim3(NBLK), dim3(256), args, 0, stream);
  if (rc != hipSuccess) {
    for (int tau = 0; tau <= TT; ++tau)
      lstm_kernel<false><<<NBLK, 256, 0, stream>>>(wh0, wx1, wh1, X0c, wxb1,
                                                   h0t, h1t, cgl, outf, hc, bs, tau, tau + 1);
  }

  // logits = out_h1 @ emb^T  (f32)
  gemm_f16_kernel<float, false><<<dim3(250, 32), 256, 0, stream>>>(
      (const _Float16*)outf, (const _Float16*)emb16, out, nullptr, VOCABN);
}

// Round 19
// 3960.843 us; speedup vs baseline: 1.0507x; 1.0507x over previous
//
#include <hip/hip_runtime.h>
#include <hip/hip_fp16.h>

#define HID    1024
#define G4     4096
#define TT     512
#define BB     8
#define VOCABN 32000
#define NBLK   256

typedef _Float16 f16x2 __attribute__((ext_vector_type(2)));
typedef _Float16 f16x8 __attribute__((ext_vector_type(8)));
typedef float    f32x4 __attribute__((ext_vector_type(4)));
typedef unsigned long long u64;

union U2F { u64 q[2]; f16x8 v; };

__device__ __forceinline__ float sigf(float x) { return 1.0f / (1.0f + expf(-x)); }

// async global->LDS, 16B per lane (HW: wave-uniform LDS base + lane*16)
__device__ __forceinline__ void gll16(const _Float16* g, _Float16* l) {
#if __has_builtin(__builtin_amdgcn_global_load_lds)
  __builtin_amdgcn_global_load_lds(
      (const __attribute__((address_space(1))) void*)g,
      (__attribute__((address_space(3))) void*)l, 16, 0, 0);
#else
  *(f32x4*)l = *(const f32x4*)g;
#endif
}

// ---------------- f32 -> f16 convert ----------------
__global__ void cvt_f16_kernel(const float* __restrict__ src, __half* __restrict__ dst, int n4) {
  int i = blockIdx.x * blockDim.x + threadIdx.x;
  int stride = gridDim.x * blockDim.x;
  for (; i < n4; i += stride) {
    f32x4 v = ((const f32x4*)src)[i];
    ((__half2*)dst)[2 * i]     = __floats2half2_rn(v[0], v[1]);
    ((__half2*)dst)[2 * i + 1] = __floats2half2_rn(v[2], v[3]);
  }
}

// ---------------- embedding gather: xe[t*8+b] = emb16[x[b][t]] ----------------
__global__ void gather_kernel(const int* __restrict__ x, const __half* __restrict__ emb,
                              __half* __restrict__ xe) {
  int gid = blockIdx.x * 256 + threadIdx.x;   // 4096 rows * 128 chunks of 16B
  int row = gid >> 7, ch = gid & 127;
  int t = row >> 3, b = row & 7;
  int tok = x[b * TT + t];
  ((f32x4*)(xe + (size_t)row * HID))[ch] = ((const f32x4*)(emb + (size_t)tok * HID))[ch];
}

__device__ __forceinline__ void storeC(float* p, float v)  { *p = v; }
__device__ __forceinline__ void storeC(__half* p, float v) { *p = __float2half(v); }

// ------- 128x128 f16 MFMA GEMM, global_load_lds staging -------
// C[M,N] = A[M,1024] * B[N,1024]^T (+bias). XL=true: X0T layout [tau][gate][unit][batch].
// LDS linear [128][32] (gload_lds needs contiguous dest: lane tid writes tid*16B).
template <typename CT, bool XL>
__global__ void __launch_bounds__(256) gemm_f16_kernel(
    const _Float16* __restrict__ A, const _Float16* __restrict__ B,
    CT* __restrict__ C, const float* __restrict__ bias, int N)
{
  __shared__ _Float16 As[128 * 32];
  __shared__ _Float16 Bs[128 * 32];
  const int tid = threadIdx.x;
  const int tn = blockIdx.x, tm = blockIdx.y;
  const int wave = tid >> 6, lane = tid & 63;
  const int wm = wave >> 1, wn = wave & 1;
  const int lr = lane & 15, lk = ((lane >> 4) << 3);
  const _Float16* Ab = A + (size_t)tm * 128 * HID;
  const _Float16* Bb = B + (size_t)tn * 128 * HID;
  const int r0 = tid >> 2, c8 = (tid & 3) * 8;
  f32x4 acc[4][4] = {};
  for (int kt = 0; kt < 32; ++kt) {
    __syncthreads();                       // LDS consumers of prev tile done
    const int ko = kt * 32 + c8;
    gll16(Ab + (size_t)r0 * HID + ko,        As + tid * 8);
    gll16(Ab + (size_t)(64 + r0) * HID + ko, As + 2048 + tid * 8);
    gll16(Bb + (size_t)r0 * HID + ko,        Bs + tid * 8);
    gll16(Bb + (size_t)(64 + r0) * HID + ko, Bs + 2048 + tid * 8);
    __syncthreads();                       // drains vmcnt (loads landed in LDS)
    f16x8 af[4], bf[4];
    #pragma unroll
    for (int m = 0; m < 4; ++m) af[m] = *(const f16x8*)(As + (wm * 64 + m * 16 + lr) * 32 + lk);
    #pragma unroll
    for (int n = 0; n < 4; ++n) bf[n] = *(const f16x8*)(Bs + (wn * 64 + n * 16 + lr) * 32 + lk);
    #pragma unroll
    for (int m = 0; m < 4; ++m)
      #pragma unroll
      for (int n = 0; n < 4; ++n)
        acc[m][n] = __builtin_amdgcn_mfma_f32_16x16x32_f16(af[m], bf[n], acc[m][n], 0, 0, 0);
  }
  const int mrow = ((lane >> 4) << 2);
  #pragma unroll
  for (int n = 0; n < 4; ++n) {
    int gc = tn * 128 + wn * 64 + n * 16 + lr;
    float bc = bias ? bias[gc] : 0.0f;
    #pragma unroll
    for (int m = 0; m < 4; ++m) {
      int gr0 = tm * 128 + wm * 64 + m * 16 + mrow;
      #pragma unroll
      for (int r = 0; r < 4; ++r) {
        float v = acc[m][n][r] + bc;
        if constexpr (XL) {
          int gr = gr0 + r;
          int idx = ((gr >> 3) * 4 + (gc >> 10)) * 8192 + (gc & 1023) * 8 + (gr & 7);
          storeC(C + idx, v);
        } else {
          storeC(C + (size_t)(gr0 + r) * N + gc, v);
        }
      }
    }
  }
}

// ---------------- persistent LSTM (R17-proven: 3.37 ms) ----------------
// 256 WGs x 256 threads (4 waves = 4 K-quarters). Block owns 4 units/layer.
// Weights as persistent MFMA A-fragments in VGPRs; h [slot][b][k] f16 at LLC.
// h loads: global_load_dwordx4 sc0 sc1 (cache-bypass, line-perfect).
// X0 prefetched post-flag; cell in regs; ONE barrier/tick + subset polling.
template <bool COOP>
__global__ void __launch_bounds__(256, 1) lstm_kernel(
    const __half* __restrict__ wh0, const __half* __restrict__ wx1, const __half* __restrict__ wh1,
    const __half* __restrict__ X0T, const float* __restrict__ wxb1,
    u64* __restrict__ h0t, u64* __restrict__ h1t, float* __restrict__ cgl,
    __half* __restrict__ outf, float* __restrict__ hc_out, unsigned* __restrict__ bs,
    int tau0, int tau1)
{
  __shared__ float part[8 * 16 * 9];   // [wave*2+layer][gaterow][batch(pad 9)]

  const int tid  = threadIdx.x;
  const int u0   = blockIdx.x * 4;
  const int wv   = tid >> 6, lane = tid & 63;
  const int rr   = lane & 15;               // gate-row: g = rr&3, uu = rr>>2
  const int kc   = (lane >> 4) * 8;         // k-chunk within K=32
  const int bcol = lane & 7;                // batch col (cols 8-15 duplicate 0-7)

  // ---- pin weights as A-fragments: wave wv holds k in [wv*256, wv*256+256) ----
  f16x8 w0f[8], w1f[8], w2f[8];
  {
    const size_t wrow = (size_t)((rr & 3) * HID + u0 + (rr >> 2)) * HID;
    #pragma unroll
    for (int m = 0; m < 8; ++m) {
      const int kb = wv * 256 + m * 32 + kc;
      w0f[m] = *(const f16x8*)(wh0 + wrow + kb);
      w1f[m] = *(const f16x8*)(wx1 + wrow + kb);
      w2f[m] = *(const f16x8*)(wh1 + wrow + kb);
    }
  }

  float bi0 = 0, bi1 = 0, bi2 = 0, bi3 = 0;
  if (tid >= 32 && tid < 64) {
    int uu = (tid >> 3) & 3, u = u0 + uu;
    bi0 = wxb1[u]; bi1 = wxb1[HID + u]; bi2 = wxb1[2 * HID + u]; bi3 = wxb1[3 * HID + u];
  }

  // cell state: register in COOP (thread owns (l,uu,b) across all ticks)
  float creg = 0.0f;
  if constexpr (!COOP) {
    if (tid < 64) {
      const int l = tid >> 5, uu = (tid >> 3) & 3, b = tid & 7;
      creg = cgl[(size_t)l * (HID * BB) + (u0 + uu) * BB + b];
    }
  }

  // X0 prefetch registers (COOP): hold X0[tau] for the upcoming tick
  float x0p0 = 0, x0p1 = 0, x0p2 = 0, x0p3 = 0;
  if constexpr (COOP) {
    if (tid < 32 && tau0 < TT) {
      const __half* xq = X0T + (size_t)tau0 * 4 * 8192 + u0 * 8 + tid;
      x0p0 = __half2float(xq[0]);
      x0p1 = __half2float(xq[8192]);
      x0p2 = __half2float(xq[2 * 8192]);
      x0p3 = __half2float(xq[3 * 8192]);
    }
  }

  for (int tau = tau0; tau < tau1; ++tau) {
    // X0 values for this tick: from prefetch (COOP) or loaded inline (fallback)
    float x0r0 = 0, x0r1 = 0, x0r2 = 0, x0r3 = 0;
    if constexpr (COOP) {
      x0r0 = x0p0; x0r1 = x0p1; x0r2 = x0p2; x0r3 = x0p3;
    } else {
      if (tid < 32 && tau < TT) {
        const __half* xp = X0T + (size_t)tau * 4 * 8192 + u0 * 8 + tid;
        x0r0 = __half2float(xp[0]);
        x0r1 = __half2float(xp[8192]);
        x0r2 = __half2float(xp[2 * 8192]);
        x0r3 = __half2float(xp[3 * 8192]);
      }
    }

    // ---- B-fragment loads from LLC: h0[tau-1], h1[tau-2] (dwordx4, cache-bypass) ----
    U2F hf0[8], hf1[8];
    {
      const u64* s0 = h0t + ((tau - 1) & 1) * 2048 + bcol * 256;
      const u64* s1 = h1t + (tau & 1) * 2048 + bcol * 256;
      #pragma unroll
      for (int m = 0; m < 8; ++m) {
        const int ki = (wv * 256 + m * 32 + kc) >> 2;
        asm volatile("global_load_dwordx4 %0, %1, off sc0 sc1"
                     : "=v"(hf0[m].v) : "v"(s0 + ki));
        asm volatile("global_load_dwordx4 %0, %1, off sc0 sc1"
                     : "=v"(hf1[m].v) : "v"(s1 + ki));
      }
      asm volatile("s_waitcnt vmcnt(0)" ::: "memory");
      __builtin_amdgcn_sched_barrier(0);
    }

    // ---- gates: acc0 = wh0.h0 ; acc1 = wx1.h0 + wh1.h1 (K-quarter partials) ----
    f32x4 a0 = {0.f, 0.f, 0.f, 0.f}, a1 = {0.f, 0.f, 0.f, 0.f};
    #pragma unroll
    for (int m = 0; m < 8; ++m) {
      a0 = __builtin_amdgcn_mfma_f32_16x16x32_f16(w0f[m], hf0[m].v, a0, 0, 0, 0);
      a1 = __builtin_amdgcn_mfma_f32_16x16x32_f16(w1f[m], hf0[m].v, a1, 0, 0, 0);
      a1 = __builtin_amdgcn_mfma_f32_16x16x32_f16(w2f[m], hf1[m].v, a1, 0, 0, 0);
    }
    // C layout: lane holds C[row=(lane>>4)*4+r][col=lane&15]; cols 8-15 garbage
    if ((lane & 15) < 8) {
      const int rb = (lane >> 4) * 4;
      #pragma unroll
      for (int r = 0; r < 4; ++r) {
        part[((wv * 2 + 0) * 16 + rb + r) * 9 + bcol] = a0[r];
        part[((wv * 2 + 1) * 16 + rb + r) * 9 + bcol] = a1[r];
      }
    }
    __syncthreads();   // the ONE block sync per tick

    // ---- update: 64 threads (wave 0) = 2 layers x 4 units x 8 batch ----
    float hn = 0.0f;
    bool act = false;
    if (tid < 64) {
      const int l = tid >> 5, uu = (tid >> 3) & 3, b = tid & 7;
      act = (l == 0) ? (tau < TT) : (tau >= 1);
      if (act) {
        float gs[4];
        #pragma unroll
        for (int g = 0; g < 4; ++g) {
          float s = 0.f;
          #pragma unroll
          for (int w = 0; w < 4; ++w)
            s += part[((w * 2 + l) * 16 + uu * 4 + g) * 9 + b];
          gs[g] = s;
        }
        float gi = gs[0], gf = gs[1], gg_ = gs[2], go = gs[3];
        if (l == 0) { gi += x0r0; gf += x0r1; gg_ += x0r2; go += x0r3; }
        else        { gi += bi0;  gf += bi1;  gg_ += bi2;  go += bi3;  }
        float co = creg;
        float cn = sigf(gf) * co + sigf(gi) * tanhf(gg_);
        hn = sigf(go) * tanhf(co);   // quirk: tanh of OLD cell
        creg = cn;
        const int u = u0 + uu;
        if (l == 1) {
          if (tau == TT) {            // final h1, c1
            hc_out[(size_t)(BB * HID) + b * HID + u] = hn;
            hc_out[3 * (size_t)(BB * HID) + b * HID + u] = cn;
          }
        } else if (tau == TT - 1) {   // final h0, c0
          hc_out[(size_t)b * HID + u] = hn;
          hc_out[2 * (size_t)(BB * HID) + b * HID + u] = cn;
        }
      }
      // pack 4 units into one u64 via shuffles; uu==0 lanes store (reuses l,uu,b)
      float s8 = __shfl_xor(hn, 8, 64);                 // partner uu^1
      __half2 p2 = __floats2half2_rn(hn, s8);
      unsigned pu; __builtin_memcpy(&pu, &p2, 4);
      unsigned q16 = __shfl_xor(pu, 16, 64);            // (uu+2, uu+3)
      u64 gr = (u64)pu | ((u64)q16 << 32);
      {
        const int l = tid >> 5, b = tid & 7;
        if (((tid >> 3) & 3) == 0 && act) {
          u64* dst = (l == 0)
              ? h0t + (tau & 1) * 2048 + b * 256 + (u0 >> 2)
              : h1t + ((tau - 1) & 1) * 2048 + b * 256 + (u0 >> 2);
          __hip_atomic_store(dst, gr, __ATOMIC_RELAXED, __HIP_MEMORY_SCOPE_AGENT);
        }
      }
    }

    if constexpr (COOP) {
      const int tick = tau - tau0 + 1;
      if (wv == 0) {
        asm volatile("s_waitcnt vmcnt(0)" ::: "memory");   // h stores acked at LLC
        if (tid == 0)
          __hip_atomic_store(&bs[blockIdx.x], (unsigned)tick,
                             __ATOMIC_RELAXED, __HIP_MEMORY_SCOPE_AGENT);
      }
      // X0 prefetch for tau+1 AFTER own flag is out (HBM latency overlaps poll)
      if (tid < 32 && tau + 1 < TT) {
        const __half* xq = X0T + (size_t)(tau + 1) * 4 * 8192 + u0 * 8 + tid;
        x0p0 = __half2float(xq[0]);
        x0p1 = __half2float(xq[8192]);
        x0p2 = __half2float(xq[2 * 8192]);
        x0p3 = __half2float(xq[3 * 8192]);
      }
      // outf store also off the flag path (no consumer in-kernel)
      if (tid >= 32 && tid < 64 && act) {
        const int uu = (tid >> 3) & 3, b = tid & 7;
        outf[((size_t)b * TT + (tau - 1)) * HID + u0 + uu] = __float2half(hn);
      }
      // dependency-subset poll: wave wv waits only its 64 producer blocks
      {
        const unsigned* fp = bs + wv * 64;
        int guard = 0;
        for (;;) {
          unsigned fa = __hip_atomic_load(&fp[lane], __ATOMIC_RELAXED, __HIP_MEMORY_SCOPE_AGENT);
          if (__all((int)fa >= tick)) break;
          if (++guard > 100000) break;   // failsafe: wrong answer, not a hang
          __builtin_amdgcn_s_sleep(1);
        }
        asm volatile("" ::: "memory");
      }
    } else {
      if (tid >= 32 && tid < 64 && act) {
        const int uu = (tid >> 3) & 3, b = tid & 7;
        outf[((size_t)b * TT + (tau - 1)) * HID + u0 + uu] = __float2half(hn);
      }
      if (tid < 64) {
        const int l = tid >> 5, uu = (tid >> 3) & 3, b = tid & 7;
        cgl[(size_t)l * (HID * BB) + (u0 + uu) * BB + b] = creg;
      }
      __syncthreads();
    }
  }
}

extern "C" void kernel_launch(void* const* d_in, const int* in_sizes, int n_in,
                              void* d_out, int out_size, void* d_ws, size_t ws_size,
                              hipStream_t stream) {
  (void)in_sizes; (void)n_in; (void)out_size; (void)ws_size;
  const int*   x    = (const int*)  d_in[0];
  const float* embW = (const float*)d_in[1];
  const float* wxw  = (const float*)d_in[2];
  const float* wxb  = (const float*)d_in[3];
  const float* whw  = (const float*)d_in[4];
  float* out = (float*)d_out;

  char* ws = (char*)d_ws;
  size_t off = 0;
  auto alloc = [&](size_t bytes) { char* p = ws + off; off += (bytes + 255) & ~(size_t)255; return p; };
  __half*   emb16 = (__half*)alloc((size_t)VOCABN * HID * 2);
  __half*   xe16  = (__half*)alloc((size_t)4096 * HID * 2);
  __half*   wxw16 = (__half*)alloc((size_t)2 * G4 * HID * 2);
  __half*   whw16 = (__half*)alloc((size_t)2 * G4 * HID * 2);
  __half*   X0T   = (__half*)alloc((size_t)4096 * G4 * 2);
  __half*   outf  = (__half*)alloc((size_t)4096 * HID * 2);
  u64*      h0t   = (u64*)  alloc((size_t)2 * 2048 * 8);   // [slot][b][k] f16
  u64*      h1t   = (u64*)  alloc((size_t)2 * 2048 * 8);
  float*    cgl   = (float*) alloc((size_t)2 * HID * BB * 4);
  unsigned* bs    = (unsigned*)alloc(NBLK * 4);

  cvt_f16_kernel<<<2048, 256, 0, stream>>>(embW, emb16, VOCABN * HID / 4);
  cvt_f16_kernel<<<1024, 256, 0, stream>>>(wxw, wxw16, 2 * G4 * HID / 4);
  cvt_f16_kernel<<<1024, 256, 0, stream>>>(whw, whw16, 2 * G4 * HID / 4);
  gather_kernel<<<2048, 256, 0, stream>>>(x, emb16, xe16);
  hipMemsetAsync(h0t, 0, (size_t)2 * 2048 * 8, stream);
  hipMemsetAsync(h1t, 0, (size_t)2 * 2048 * 8, stream);
  hipMemsetAsync(cgl, 0, (size_t)2 * HID * BB * 4, stream);
  hipMemsetAsync(bs,  0, NBLK * 4, stream);

  // X0T[tau][gate][unit][batch] = xe @ wx0^T + b0   (f16)
  gemm_f16_kernel<__half, true><<<dim3(32, 32), 256, 0, stream>>>(
      (const _Float16*)xe16, (const _Float16*)wxw16, X0T, wxb, G4);

  const __half* wh0 = whw16;
  const __half* wx1 = wxw16 + (size_t)G4 * HID;
  const __half* wh1 = whw16 + (size_t)G4 * HID;
  const __half* X0c = X0T;
  const float*  wxb1 = wxb + G4;
  float* hc = out + (size_t)4096 * VOCABN;
  int tb = 0, te = TT + 1;
  void* args[] = {(void*)&wh0, (void*)&wx1, (void*)&wh1, (void*)&X0c, (void*)&wxb1,
                  (void*)&h0t, (void*)&h1t, (void*)&cgl, (void*)&outf, (void*)&hc,
                  (void*)&bs, (void*)&tb, (void*)&te};
  hipError_t rc = hipLaunchCooperativeKernel(
      reinterpret_cast<void*>(&lstm_kernel<true>), dim3(NBLK), dim3(256), args, 0, stream);
  if (rc != hipSuccess) {
    for (int tau = 0; tau <= TT; ++tau)
      lstm_kernel<false><<<NBLK, 256, 0, stream>>>(wh0, wx1, wh1, X0c, wxb1,
                                                   h0t, h1t, cgl, outf, hc, bs, tau, tau + 1);
  }

  // logits = out_h1 @ emb^T  (f32)
  gemm_f16_kernel<float, false><<<dim3(250, 32), 256, 0, stream>>>(
      (const _Float16*)outf, (const _Float16*)emb16, out, nullptr, VOCABN);
}